// Round 1
// baseline (349.834 us; speedup 1.0000x reference)
//
#include <hip/hip_runtime.h>
#include <hip/hip_bf16.h>
#include <math.h>

typedef __bf16 bf16;
typedef bf16 bf16x8 __attribute__((ext_vector_type(8)));
typedef bf16 bf16x4v __attribute__((ext_vector_type(4)));
typedef float f32x4 __attribute__((ext_vector_type(4)));

#define GLD16(g, l) __builtin_amdgcn_global_load_lds(                          \
    (__attribute__((address_space(1))) void*)(g),                              \
    (__attribute__((address_space(3))) void*)(l), 16, 0, 0)

#define MFMA16(a, b, c) __builtin_amdgcn_mfma_f32_16x16x32_bf16((a), (b), (c), 0, 0, 0)

#if __has_builtin(__builtin_amdgcn_exp2f)
#define EXP2F(x) __builtin_amdgcn_exp2f(x)
#else
#define EXP2F(x) exp2f(x)
#endif

__device__ __forceinline__ f32x4 shfl_xor4(f32x4 a, int m) {
  f32x4 r;
  #pragma unroll
  for (int i = 0; i < 4; i++) r[i] = __shfl_xor(a[i], m);
  return r;
}

// ---------------- cast f32 -> bf16 (vectorized) ----------------
__global__ void cast_f32_bf16(const float* __restrict__ in, bf16* __restrict__ out, int n4) {
  int i = blockIdx.x * blockDim.x + threadIdx.x;
  if (i < n4) {
    float4 v = ((const float4*)in)[i];
    bf16x4v o;
    o.x = (bf16)v.x; o.y = (bf16)v.y; o.z = (bf16)v.z; o.w = (bf16)v.w;
    ((bf16x4v*)out)[i] = o;
  }
}

// ---------------- transpose + cast + scale: out[off + c][r] = in[r][c]*scale ----------------
__global__ void transpose_cast(const float* __restrict__ in, bf16* __restrict__ out,
                               int colsIn, int outStride, int outRowOff, float scale) {
  __shared__ float t[32][33];
  int c0 = blockIdx.x * 32, r0 = blockIdx.y * 32;
  int tx = threadIdx.x, ty = threadIdx.y;  // block (32,8)
  #pragma unroll
  for (int i = 0; i < 32; i += 8)
    t[ty + i][tx] = in[(size_t)(r0 + ty + i) * colsIn + (c0 + tx)];
  __syncthreads();
  #pragma unroll
  for (int i = 0; i < 32; i += 8)
    out[(size_t)(outRowOff + c0 + ty + i) * outStride + (r0 + tx)] = (bf16)(t[tx][ty + i] * scale);
}

// ---------------- V -> V^T global: Vg[(b*4+kvh)][d][n] = QKV[b*2048+n][2560+kvh*128+d] ----------------
__global__ void transpose_v(const bf16* __restrict__ QKV, bf16* __restrict__ Vg) {
  __shared__ bf16 t[32][34];
  int n0 = blockIdx.x * 32, d0 = blockIdx.y * 32;
  int bk = blockIdx.z;
  int b = bk >> 2, kvh = bk & 3;
  const bf16* src = QKV + (size_t)b * 2048 * 3072 + 2560 + kvh * 128;
  bf16* dst = Vg + (size_t)bk * 128 * 2048;
  int tx = threadIdx.x, ty = threadIdx.y;  // block (32,8)
  #pragma unroll
  for (int i = 0; i < 32; i += 8)
    t[ty + i][tx] = src[(size_t)(n0 + ty + i) * 3072 + (d0 + tx)];
  __syncthreads();
  #pragma unroll
  for (int i = 0; i < 32; i += 8)
    dst[(size_t)(d0 + ty + i) * 2048 + (n0 + tx)] = t[tx][ty + i];
}

// ---------------- m97-style GEMM: A[M][K] bf16, Bt[N][K] bf16 -> C[M][N] ----------------
template <typename OutT>
__global__ __launch_bounds__(256, 2) void gemm_bt(const bf16* __restrict__ A,
                                                  const bf16* __restrict__ Bt,
                                                  OutT* __restrict__ C,
                                                  int M, int N, int K) {
  __shared__ __attribute__((aligned(16))) bf16 As[128 * 32];
  __shared__ __attribute__((aligned(16))) bf16 Bs[128 * 32];
  const int tid = threadIdx.x;
  const int lane = tid & 63;
  const int wave = tid >> 6;
  const int wm = wave >> 1, wn = wave & 1;
  const int l15 = lane & 15, quad = lane >> 4;
  const int rowBase = blockIdx.y * 128;
  const int colBase = blockIdx.x * 128;

  f32x4 acc[4][4] = {};

  const int cb0 = wave * 64;
  const int c0 = cb0 + lane;
  const int c1 = c0 + 256;
  const bf16* a0 = A + (size_t)(rowBase + (c0 >> 2)) * K + (c0 & 3) * 8;
  const bf16* a1 = A + (size_t)(rowBase + (c1 >> 2)) * K + (c1 & 3) * 8;
  const bf16* b0 = Bt + (size_t)(colBase + (c0 >> 2)) * K + (c0 & 3) * 8;
  const bf16* b1 = Bt + (size_t)(colBase + (c1 >> 2)) * K + (c1 & 3) * 8;
  bf16* lA0 = &As[cb0 * 8];
  bf16* lA1 = &As[(cb0 + 256) * 8];
  bf16* lB0 = &Bs[cb0 * 8];
  bf16* lB1 = &Bs[(cb0 + 256) * 8];

  for (int k0 = 0; k0 < K; k0 += 32) {
    GLD16(a0 + k0, lA0);
    GLD16(a1 + k0, lA1);
    GLD16(b0 + k0, lB0);
    GLD16(b1 + k0, lB1);
    __syncthreads();
    bf16x8 af[4], bfr[4];
    #pragma unroll
    for (int i = 0; i < 4; i++)
      af[i] = *(const bf16x8*)&As[(wm * 64 + i * 16 + l15) * 32 + quad * 8];
    #pragma unroll
    for (int i = 0; i < 4; i++)
      bfr[i] = *(const bf16x8*)&Bs[(wn * 64 + i * 16 + l15) * 32 + quad * 8];
    #pragma unroll
    for (int i = 0; i < 4; i++)
      #pragma unroll
      for (int j = 0; j < 4; j++)
        acc[i][j] = MFMA16(af[i], bfr[j], acc[i][j]);
    __syncthreads();
  }

  #pragma unroll
  for (int i = 0; i < 4; i++) {
    int row = rowBase + wm * 64 + i * 16 + quad * 4;
    #pragma unroll
    for (int j = 0; j < 4; j++) {
      int col = colBase + wn * 64 + j * 16 + l15;
      #pragma unroll
      for (int r = 0; r < 4; r++)
        C[(size_t)(row + r) * N + col] = (OutT)acc[i][j][r];
    }
  }
}

// ---------------- flash-style GQA attention v3: double-buffered 2-phase schedule ----------------
// Q pre-scaled by SCALE*log2(e) (folded into Wq) -> scores in log2 domain.
// K staged via global_load_lds into XOR-swizzled Kl[2][64][128]; V^T from Vg into Vt[2][128][64].
// Per k-tile: issue GLD16 for tile t+1 into buf^1, compute tile t from buf, ONE barrier
// (vmcnt drain lands after compute -> staging latency hidden). T3 "minimum 2-phase" template.
// P buffer holds only the 16 rows the current mt-half consumes -> Pl shrinks to fit 2 blocks/CU.
#define MASKV (-1e30f)

__global__ __launch_bounds__(256, 2) void gqa_attn(const bf16* __restrict__ QKV,
                                                   const bf16* __restrict__ Vg,
                                                   bf16* __restrict__ Obf) {
  __shared__ __attribute__((aligned(16))) bf16 Kl[2 * 64 * 128];   // dbuf [key][hd], chunk c' = c ^ (key&7)
  __shared__ __attribute__((aligned(16))) bf16 Vt[2 * 128 * 64];   // dbuf [hd][key], chunk c' = c ^ (d&7)
  __shared__ __attribute__((aligned(16))) bf16 Pl[4][16 * 72];     // per-wave P half-tile, stride 72 (16B-aligned rows)

  const int tid = threadIdx.x;
  const int lane = tid & 63;
  const int wave = tid >> 6;
  const int l15 = lane & 15, quad = lane >> 4;

  // heavy/light pairing: blocks i and i+256 expected co-resident on one CU
  int bi = blockIdx.x;
  int bh = bi & 31;
  int jj = (bi & 255) >> 5;
  int qt = (bi < 256) ? (8 + jj) : (7 - jj);
  int b = bh >> 4, h = bh & 15, kvh = h >> 2;
  int q0 = qt * 128;

  const size_t rs = 3072;
  const bf16* Qb  = QKV + (size_t)b * 2048 * rs + h * 128;
  const bf16* Kb  = QKV + (size_t)b * 2048 * rs + 2048 + kvh * 128;
  const bf16* Vgb = Vg + (size_t)(b * 4 + kvh) * 128 * 2048;

  // Q fragments (already scaled): wave owns rows [q0+wave*32, +32)
  bf16x8 qf[2][4];
  #pragma unroll
  for (int mt = 0; mt < 2; mt++) {
    int row = q0 + wave * 32 + mt * 16 + l15;
    #pragma unroll
    for (int ks = 0; ks < 4; ks++)
      qf[mt][ks] = *(const bf16x8*)&Qb[(size_t)row * rs + ks * 32 + quad * 8];
  }

  // DMA staging pointers: swizzle folded into per-lane GLOBAL address; LDS base wave-uniform.
  const bf16* kp[4]; const bf16* vp[4];
  int klo[4], vlo[4];
  #pragma unroll
  for (int t = 0; t < 4; t++) {
    int keyl = wave * 16 + t * 4 + (lane >> 4);
    int ck = (lane & 15) ^ (4 * (t & 1) + (lane >> 4));  // (keyl&7) = 4*(t&1)+(lane>>4)
    kp[t] = Kb + (size_t)keyl * rs + ck * 8;
    klo[t] = (wave * 16 + t * 4) * 128;
    int dl = wave * 32 + t * 8 + (lane >> 3);
    int cv = (lane & 7) ^ (lane >> 3);                   // (dl&7) = lane>>3
    vp[t] = Vgb + (size_t)dl * 2048 + cv * 8;
    vlo[t] = (wave * 32 + t * 8) * 64;
  }

  f32x4 oacc[2][8] = {};
  f32x4 mrow[2], lrow[2];
  #pragma unroll
  for (int mt = 0; mt < 2; mt++)
    #pragma unroll
    for (int r = 0; r < 4; r++) { mrow[mt][r] = MASKV; lrow[mt][r] = 0.f; }

  const int nkt = 2 * qt + 2;
  const int myrow_hi = q0 + wave * 32 + 31;

  // prologue: stage tile 0 into buffer 0, publish
  #pragma unroll
  for (int t = 0; t < 4; t++) { GLD16(kp[t], Kl + klo[t]); kp[t] += 64 * rs; }
  #pragma unroll
  for (int t = 0; t < 4; t++) { GLD16(vp[t], Vt + vlo[t]); vp[t] += 64; }
  __syncthreads();

  for (int kt = 0; kt < nkt; kt++) {
    const int cur = kt & 1;
    const int k0 = kt * 64;

    // issue next-tile staging FIRST (into the other buffer); latency hides under compute
    if (kt + 1 < nkt) {
      const int nb = (cur ^ 1) * 8192;
      #pragma unroll
      for (int t = 0; t < 4; t++) { GLD16(kp[t], Kl + nb + klo[t]); kp[t] += 64 * rs; }
      #pragma unroll
      for (int t = 0; t < 4; t++) { GLD16(vp[t], Vt + nb + vlo[t]); vp[t] += 64; }
    }

    if (k0 <= myrow_hi) {  // wave not fully masked for this tile
      const bf16* Kc = Kl + cur * 8192;
      const bf16* Vc = Vt + cur * 8192;

      // S = Q K^T (log2 domain)
      f32x4 s[2][4] = {};
      __builtin_amdgcn_s_setprio(1);
      #pragma unroll
      for (int ks = 0; ks < 4; ks++) {
        #pragma unroll
        for (int nt = 0; nt < 4; nt++) {
          bf16x8 kf = *(const bf16x8*)&Kc[(nt * 16 + l15) * 128 +
                                          (((ks * 4 + quad) ^ (l15 & 7)) * 8)];
          s[0][nt] = MFMA16(qf[0][ks], kf, s[0][nt]);
          s[1][nt] = MFMA16(qf[1][ks], kf, s[1][nt]);
        }
      }
      __builtin_amdgcn_s_setprio(0);

      // causal mask: only the last two k-tiles can intersect the diagonal (uniform branch)
      if (kt >= nkt - 2) {
        #pragma unroll
        for (int mt = 0; mt < 2; mt++) {
          int rowb = q0 + wave * 32 + mt * 16 + quad * 4;
          #pragma unroll
          for (int nt = 0; nt < 4; nt++) {
            int col = k0 + nt * 16 + l15;
            #pragma unroll
            for (int r = 0; r < 4; r++)
              if (col > rowb + r) s[mt][nt][r] = MASKV;
          }
        }
      }

      // online softmax (log2 domain) + PV, split per mt-half (P buffer holds 16 rows)
      #pragma unroll
      for (int mt = 0; mt < 2; mt++) {
        f32x4 mx = s[mt][0];
        #pragma unroll
        for (int nt = 1; nt < 4; nt++)
          #pragma unroll
          for (int r = 0; r < 4; r++) mx[r] = fmaxf(mx[r], s[mt][nt][r]);
        #pragma unroll
        for (int d = 1; d < 16; d <<= 1) {
          f32x4 o = shfl_xor4(mx, d);
          #pragma unroll
          for (int r = 0; r < 4; r++) mx[r] = fmaxf(mx[r], o[r]);
        }
        f32x4 mnew, alpha;
        #pragma unroll
        for (int r = 0; r < 4; r++) {
          mnew[r] = fmaxf(mrow[mt][r], mx[r]);
          alpha[r] = EXP2F(mrow[mt][r] - mnew[r]);
        }
        f32x4 rsum = {0.f, 0.f, 0.f, 0.f};
        #pragma unroll
        for (int nt = 0; nt < 4; nt++)
          #pragma unroll
          for (int r = 0; r < 4; r++) {
            float p = EXP2F(s[mt][nt][r] - mnew[r]);
            s[mt][nt][r] = p;
            rsum[r] += p;
          }
        #pragma unroll
        for (int d = 1; d < 16; d <<= 1) rsum += shfl_xor4(rsum, d);
        #pragma unroll
        for (int r = 0; r < 4; r++) {
          lrow[mt][r] = lrow[mt][r] * alpha[r] + rsum[r];
          mrow[mt][r] = mnew[r];
        }
        #pragma unroll
        for (int no = 0; no < 8; no++)
          #pragma unroll
          for (int r = 0; r < 4; r++) oacc[mt][no][r] *= alpha[r];

        // P: C-layout -> per-wave LDS (A-layout consumable); 16 rows, stride 72
        #pragma unroll
        for (int nt = 0; nt < 4; nt++)
          #pragma unroll
          for (int r = 0; r < 4; r++)
            Pl[wave][(quad * 4 + r) * 72 + nt * 16 + l15] = (bf16)s[mt][nt][r];

        // O[mt] += P V
        __builtin_amdgcn_s_setprio(1);
        #pragma unroll
        for (int ks2 = 0; ks2 < 2; ks2++) {
          bf16x8 pf = *(const bf16x8*)&Pl[wave][l15 * 72 + ks2 * 32 + quad * 8];
          #pragma unroll
          for (int no = 0; no < 8; no++) {
            bf16x8 vf = *(const bf16x8*)&Vc[(no * 16 + l15) * 64 +
                                            (((ks2 * 4 + quad) ^ (l15 & 7)) * 8)];
            oacc[mt][no] = MFMA16(pf, vf, oacc[mt][no]);
          }
        }
        __builtin_amdgcn_s_setprio(0);
      }
    }

    // single barrier per tile: publishes tile kt+1 (vmcnt drain) AND frees buf[cur] for kt+2
    __syncthreads();
  }

  // epilogue: normalize and write bf16
  #pragma unroll
  for (int mt = 0; mt < 2; mt++) {
    f32x4 linv;
    #pragma unroll
    for (int r = 0; r < 4; r++) linv[r] = 1.0f / lrow[mt][r];
    int row = q0 + wave * 32 + mt * 16 + quad * 4;
    #pragma unroll
    for (int no = 0; no < 8; no++) {
      int col = h * 128 + no * 16 + l15;
      #pragma unroll
      for (int r = 0; r < 4; r++)
        Obf[(size_t)(b * 2048 + row + r) * 2048 + col] = (bf16)(oacc[mt][no][r] * linv[r]);
    }
  }
}

extern "C" void kernel_launch(void* const* d_in, const int* in_sizes, int n_in,
                              void* d_out, int out_size, void* d_ws, size_t ws_size,
                              hipStream_t stream) {
  const float* x  = (const float*)d_in[0];
  // d_in[1] = mask: always causal tril; handled analytically.
  const float* Wq = (const float*)d_in[2];
  const float* Wk = (const float*)d_in[3];
  const float* Wv = (const float*)d_in[4];
  const float* Wo = (const float*)d_in[5];
  float* out = (float*)d_out;

  // workspace layout (bf16 elements)
  bf16* Xb    = (bf16*)d_ws;           // 4096x2048
  bf16* Wqkvt = Xb + 8388608;          // 3072x2048 (transposed, fused Q|K|V)
  bf16* Wot   = Wqkvt + 6291456;       // 2048x2048 (transposed)
  bf16* QKV   = Wot + 4194304;         // 4096x3072
  bf16* Obf   = QKV + 12582912;        // 4096x2048
  bf16* Vg    = Obf + 8388608;         // 8 x 128 x 2048 (V^T per (b,kvh))
  // total 83,886,080 bytes

  const float qscale = (float)(0.08838834764831845 * 1.4426950408889634);

  cast_f32_bf16<<<8192, 256, 0, stream>>>(x, Xb, 2097152);
  dim3 tb(32, 8);
  transpose_cast<<<dim3(64, 64), tb, 0, stream>>>(Wq, Wqkvt, 2048, 2048, 0, qscale);
  transpose_cast<<<dim3(16, 64), tb, 0, stream>>>(Wk, Wqkvt, 512, 2048, 2048, 1.0f);
  transpose_cast<<<dim3(16, 64), tb, 0, stream>>>(Wv, Wqkvt, 512, 2048, 2560, 1.0f);
  transpose_cast<<<dim3(64, 64), tb, 0, stream>>>(Wo, Wot, 2048, 2048, 0, 1.0f);

  gemm_bt<bf16><<<dim3(24, 32), 256, 0, stream>>>(Xb, Wqkvt, QKV, 4096, 3072, 2048);
  transpose_v<<<dim3(64, 4, 8), tb, 0, stream>>>(QKV, Vg);
  gqa_attn<<<512, 256, 0, stream>>>(QKV, Vg, Obf);
  gemm_bt<float><<<dim3(16, 32), 256, 0, stream>>>(Obf, Wot, out, 4096, 2048, 2048);
}

// Round 3
// 337.037 us; speedup vs baseline: 1.0380x; 1.0380x over previous
//
#include <hip/hip_runtime.h>
#include <hip/hip_bf16.h>
#include <math.h>

typedef __bf16 bf16;
typedef bf16 bf16x8 __attribute__((ext_vector_type(8)));
typedef bf16 bf16x4v __attribute__((ext_vector_type(4)));
typedef float f32x4 __attribute__((ext_vector_type(4)));

#define GLD16(g, l) __builtin_amdgcn_global_load_lds(                          \
    (__attribute__((address_space(1))) void*)(g),                              \
    (__attribute__((address_space(3))) void*)(l), 16, 0, 0)

#define MFMA16(a, b, c) __builtin_amdgcn_mfma_f32_16x16x32_bf16((a), (b), (c), 0, 0, 0)

#if __has_builtin(__builtin_amdgcn_exp2f)
#define EXP2F(x) __builtin_amdgcn_exp2f(x)
#else
#define EXP2F(x) exp2f(x)
#endif

__device__ __forceinline__ f32x4 shfl_xor4(f32x4 a, int m) {
  f32x4 r;
  #pragma unroll
  for (int i = 0; i < 4; i++) r[i] = __shfl_xor(a[i], m);
  return r;
}

// ---------------- cast f32 -> bf16 (vectorized) ----------------
__global__ void cast_f32_bf16(const float* __restrict__ in, bf16* __restrict__ out, int n4) {
  int i = blockIdx.x * blockDim.x + threadIdx.x;
  if (i < n4) {
    float4 v = ((const float4*)in)[i];
    bf16x4v o;
    o.x = (bf16)v.x; o.y = (bf16)v.y; o.z = (bf16)v.z; o.w = (bf16)v.w;
    ((bf16x4v*)out)[i] = o;
  }
}

// ---------------- transpose + cast + scale: out[off + c][r] = in[r][c]*scale ----------------
__global__ void transpose_cast(const float* __restrict__ in, bf16* __restrict__ out,
                               int colsIn, int outStride, int outRowOff, float scale) {
  __shared__ float t[32][33];
  int c0 = blockIdx.x * 32, r0 = blockIdx.y * 32;
  int tx = threadIdx.x, ty = threadIdx.y;  // block (32,8)
  #pragma unroll
  for (int i = 0; i < 32; i += 8)
    t[ty + i][tx] = in[(size_t)(r0 + ty + i) * colsIn + (c0 + tx)];
  __syncthreads();
  #pragma unroll
  for (int i = 0; i < 32; i += 8)
    out[(size_t)(outRowOff + c0 + ty + i) * outStride + (r0 + tx)] = (bf16)(t[tx][ty + i] * scale);
}

// ---------------- V -> V^T global: Vg[(b*4+kvh)][d][n] = QKV[b*2048+n][2560+kvh*128+d] ----------------
__global__ void transpose_v(const bf16* __restrict__ QKV, bf16* __restrict__ Vg) {
  __shared__ bf16 t[32][34];
  int n0 = blockIdx.x * 32, d0 = blockIdx.y * 32;
  int bk = blockIdx.z;
  int b = bk >> 2, kvh = bk & 3;
  const bf16* src = QKV + (size_t)b * 2048 * 3072 + 2560 + kvh * 128;
  bf16* dst = Vg + (size_t)bk * 128 * 2048;
  int tx = threadIdx.x, ty = threadIdx.y;  // block (32,8)
  #pragma unroll
  for (int i = 0; i < 32; i += 8)
    t[ty + i][tx] = src[(size_t)(n0 + ty + i) * 3072 + (d0 + tx)];
  __syncthreads();
  #pragma unroll
  for (int i = 0; i < 32; i += 8)
    dst[(size_t)(d0 + ty + i) * 2048 + (n0 + tx)] = t[tx][ty + i];
}

// ---------------- m97-style GEMM: A[M][K] bf16, Bt[N][K] bf16 -> C[M][N] ----------------
template <typename OutT>
__global__ __launch_bounds__(256, 2) void gemm_bt(const bf16* __restrict__ A,
                                                  const bf16* __restrict__ Bt,
                                                  OutT* __restrict__ C,
                                                  int M, int N, int K) {
  __shared__ __attribute__((aligned(16))) bf16 As[128 * 32];
  __shared__ __attribute__((aligned(16))) bf16 Bs[128 * 32];
  const int tid = threadIdx.x;
  const int lane = tid & 63;
  const int wave = tid >> 6;
  const int wm = wave >> 1, wn = wave & 1;
  const int l15 = lane & 15, quad = lane >> 4;
  const int rowBase = blockIdx.y * 128;
  const int colBase = blockIdx.x * 128;

  f32x4 acc[4][4] = {};

  const int cb0 = wave * 64;
  const int c0 = cb0 + lane;
  const int c1 = c0 + 256;
  const bf16* a0 = A + (size_t)(rowBase + (c0 >> 2)) * K + (c0 & 3) * 8;
  const bf16* a1 = A + (size_t)(rowBase + (c1 >> 2)) * K + (c1 & 3) * 8;
  const bf16* b0 = Bt + (size_t)(colBase + (c0 >> 2)) * K + (c0 & 3) * 8;
  const bf16* b1 = Bt + (size_t)(colBase + (c1 >> 2)) * K + (c1 & 3) * 8;
  bf16* lA0 = &As[cb0 * 8];
  bf16* lA1 = &As[(cb0 + 256) * 8];
  bf16* lB0 = &Bs[cb0 * 8];
  bf16* lB1 = &Bs[(cb0 + 256) * 8];

  for (int k0 = 0; k0 < K; k0 += 32) {
    GLD16(a0 + k0, lA0);
    GLD16(a1 + k0, lA1);
    GLD16(b0 + k0, lB0);
    GLD16(b1 + k0, lB1);
    __syncthreads();
    bf16x8 af[4], bfr[4];
    #pragma unroll
    for (int i = 0; i < 4; i++)
      af[i] = *(const bf16x8*)&As[(wm * 64 + i * 16 + l15) * 32 + quad * 8];
    #pragma unroll
    for (int i = 0; i < 4; i++)
      bfr[i] = *(const bf16x8*)&Bs[(wn * 64 + i * 16 + l15) * 32 + quad * 8];
    #pragma unroll
    for (int i = 0; i < 4; i++)
      #pragma unroll
      for (int j = 0; j < 4; j++)
        acc[i][j] = MFMA16(af[i], bfr[j], acc[i][j]);
    __syncthreads();
  }

  #pragma unroll
  for (int i = 0; i < 4; i++) {
    int row = rowBase + wm * 64 + i * 16 + quad * 4;
    #pragma unroll
    for (int j = 0; j < 4; j++) {
      int col = colBase + wn * 64 + j * 16 + l15;
      #pragma unroll
      for (int r = 0; r < 4; r++)
        C[(size_t)(row + r) * N + col] = (OutT)acc[i][j][r];
    }
  }
}

// ---------------- flash-style GQA attention v5: split-K + balanced static schedule ----------------
// Inner loop = round-0 structure exactly (measured 98.5us; round-1 dbuf regressed).
// Round-0's idle was scheduling geometry: heavy/light pairing left a solo tail
// (wall = 32 tiles on the worst CUs vs 17 avg; predicted occupancy 13.3%, measured 13.58%).
// v5 (deterministic version of v4): qt>=10 split into two half-K blocks (online softmax is
// partition-independent); each writes an f32 unnormalized partial (Oacc,m,l) into workspace
// dead after GEMM1. A separate merge kernel (stream-ordered, deterministic, replay-idempotent;
// no atomics, no memset, no fences) combines the halves. BMAP orders the 704 blocks so each
// CU (bi mod 256) gets block lengths summing to exactly 34 tiles; longest block 32 -> 20 tiles.
#define MASKV (-1e30f)

// entry code = qt*4 + split*2 + half. CU c gets entries {c>>5, (c>>5)+8, (c>>5)+16}:
// g0:{16,16,2} g1:{15,15,4} g2:{14,14,6} g3:{13,13,8} g4:{12,12,10} g5:{12,11,11}
// g6:{20,14} g7:{18,16}  -- every group sums to 34 tiles.
__device__ const unsigned char BMAP[22] = {
  28, 58, 24, 50, 20, 46, 36, 32,      // e0..e7:  qt7f qt14h0 qt6f qt12h0 qt5f qt11h0 qt9f qt8f
  62, 59, 54, 51, 47, 42, 55, 63,      // e8..e15: qt15h0 qt14h1 qt13h0 qt12h1 qt11h1 qt10h0 qt13h1 qt15h1
  0, 4, 8, 12, 16, 43                  // e16..e21: qt0f qt1f qt2f qt3f qt4f qt10h1
};

#define SLOT_F32 16640  // 128*128 Oacc + 128 m + 128 l

__global__ __launch_bounds__(256, 2) void gqa_attn(const bf16* __restrict__ QKV,
                                                   const bf16* __restrict__ Vg,
                                                   bf16* __restrict__ Obf,
                                                   float* __restrict__ Part) {
  __shared__ __attribute__((aligned(16))) bf16 Kl[64 * 128];   // [key][hd], chunk c' = c ^ (key&7)
  __shared__ __attribute__((aligned(16))) bf16 Vt[128 * 64];   // [hd][key], chunk c' = c ^ (d&7)
  __shared__ __attribute__((aligned(16))) bf16 Pl[4][32 * 68]; // per-wave P, stride 68

  const int tid = threadIdx.x;
  const int lane = tid & 63;
  const int wave = tid >> 6;
  const int l15 = lane & 15, quad = lane >> 4;

  const int e = BMAP[blockIdx.x >> 5];
  const int bh = blockIdx.x & 31;
  const int qt = e >> 2;
  const int split = (e >> 1) & 1;
  const int half = e & 1;
  const int b = bh >> 4, h = bh & 15, kvh = h >> 2;
  const int q0 = qt * 128;
  const int nkt = 2 * qt + 2;
  const int kt_lo = (split && half) ? (nkt >> 1) : 0;
  const int kt_hi = (split && !half) ? (nkt >> 1) : nkt;

  const size_t rs = 3072;
  const bf16* Qb  = QKV + (size_t)b * 2048 * rs + h * 128;
  const bf16* Kb  = QKV + (size_t)b * 2048 * rs + 2048 + kvh * 128;
  const bf16* Vgb = Vg + (size_t)(b * 4 + kvh) * 128 * 2048;

  // Q fragments (already scaled): wave owns rows [q0+wave*32, +32)
  bf16x8 qf[2][4];
  #pragma unroll
  for (int mt = 0; mt < 2; mt++) {
    int row = q0 + wave * 32 + mt * 16 + l15;
    #pragma unroll
    for (int ks = 0; ks < 4; ks++)
      qf[mt][ks] = *(const bf16x8*)&Qb[(size_t)row * rs + ks * 32 + quad * 8];
  }

  // DMA staging pointers: swizzle folded into per-lane GLOBAL address; LDS base wave-uniform.
  const bf16* kp[4]; const bf16* vp[4];
  bf16* kl[4]; bf16* vl[4];
  #pragma unroll
  for (int t = 0; t < 4; t++) {
    int keyl = wave * 16 + t * 4 + (lane >> 4);
    int ck = (lane & 15) ^ (4 * (t & 1) + (lane >> 4));  // (keyl&7) = 4*(t&1)+(lane>>4)
    kp[t] = Kb + (size_t)(kt_lo * 64 + keyl) * rs + ck * 8;
    kl[t] = &Kl[(wave * 16 + t * 4) * 128];
    int dl = wave * 32 + t * 8 + (lane >> 3);
    int cv = (lane & 7) ^ (lane >> 3);                   // (dl&7) = lane>>3
    vp[t] = Vgb + (size_t)dl * 2048 + kt_lo * 64 + cv * 8;
    vl[t] = &Vt[(wave * 32 + t * 8) * 64];
  }

  f32x4 oacc[2][8] = {};
  f32x4 mrow[2], lrow[2];
  #pragma unroll
  for (int mt = 0; mt < 2; mt++)
    #pragma unroll
    for (int r = 0; r < 4; r++) { mrow[mt][r] = MASKV; lrow[mt][r] = 0.f; }

  const int myrow_hi = q0 + wave * 32 + 31;
  for (int kt = kt_lo; kt < kt_hi; kt++) {
    const int k0 = kt * 64;
    __syncthreads();  // previous tile fully consumed by all waves
    #pragma unroll
    for (int t = 0; t < 4; t++) { GLD16(kp[t], kl[t]); kp[t] += 64 * rs; }
    #pragma unroll
    for (int t = 0; t < 4; t++) { GLD16(vp[t], vl[t]); vp[t] += 64; }
    __syncthreads();  // compiler drains vmcnt before barrier -> tiles ready

    if (k0 > myrow_hi) continue;  // wave fully masked for this tile

    // S = Q K^T (log2 domain)
    f32x4 s[2][4] = {};
    #pragma unroll
    for (int ks = 0; ks < 4; ks++) {
      #pragma unroll
      for (int nt = 0; nt < 4; nt++) {
        bf16x8 kf = *(const bf16x8*)&Kl[(nt * 16 + l15) * 128 +
                                        (((ks * 4 + quad) ^ (l15 & 7)) * 8)];
        s[0][nt] = MFMA16(qf[0][ks], kf, s[0][nt]);
        s[1][nt] = MFMA16(qf[1][ks], kf, s[1][nt]);
      }
    }
    // causal mask: only the last two k-tiles can intersect the diagonal (uniform branch)
    if (kt >= nkt - 2) {
      #pragma unroll
      for (int mt = 0; mt < 2; mt++) {
        int rowb = q0 + wave * 32 + mt * 16 + quad * 4;
        #pragma unroll
        for (int nt = 0; nt < 4; nt++) {
          int col = k0 + nt * 16 + l15;
          #pragma unroll
          for (int r = 0; r < 4; r++)
            if (col > rowb + r) s[mt][nt][r] = MASKV;
        }
      }
    }
    // online softmax (log2 domain; no muls)
    #pragma unroll
    for (int mt = 0; mt < 2; mt++) {
      f32x4 mx = s[mt][0];
      #pragma unroll
      for (int nt = 1; nt < 4; nt++)
        #pragma unroll
        for (int r = 0; r < 4; r++) mx[r] = fmaxf(mx[r], s[mt][nt][r]);
      #pragma unroll
      for (int d = 1; d < 16; d <<= 1) {
        f32x4 o = shfl_xor4(mx, d);
        #pragma unroll
        for (int r = 0; r < 4; r++) mx[r] = fmaxf(mx[r], o[r]);
      }
      f32x4 mnew, alpha;
      #pragma unroll
      for (int r = 0; r < 4; r++) {
        mnew[r] = fmaxf(mrow[mt][r], mx[r]);
        alpha[r] = EXP2F(mrow[mt][r] - mnew[r]);
      }
      f32x4 rsum = {0.f, 0.f, 0.f, 0.f};
      #pragma unroll
      for (int nt = 0; nt < 4; nt++)
        #pragma unroll
        for (int r = 0; r < 4; r++) {
          float p = EXP2F(s[mt][nt][r] - mnew[r]);
          s[mt][nt][r] = p;
          rsum[r] += p;
        }
      #pragma unroll
      for (int d = 1; d < 16; d <<= 1) rsum += shfl_xor4(rsum, d);
      #pragma unroll
      for (int r = 0; r < 4; r++) {
        lrow[mt][r] = lrow[mt][r] * alpha[r] + rsum[r];
        mrow[mt][r] = mnew[r];
      }
      #pragma unroll
      for (int no = 0; no < 8; no++)
        #pragma unroll
        for (int r = 0; r < 4; r++) oacc[mt][no][r] *= alpha[r];
      // P: C-layout -> per-wave LDS (A-layout consumable); stride 68 -> conflict-free writes
      #pragma unroll
      for (int nt = 0; nt < 4; nt++)
        #pragma unroll
        for (int r = 0; r < 4; r++)
          Pl[wave][(mt * 16 + quad * 4 + r) * 68 + nt * 16 + l15] = (bf16)s[mt][nt][r];
    }
    // O += P V
    #pragma unroll
    for (int ks2 = 0; ks2 < 2; ks2++) {
      bf16x8 pf0 = *(const bf16x8*)&Pl[wave][l15 * 68 + ks2 * 32 + quad * 8];
      bf16x8 pf1 = *(const bf16x8*)&Pl[wave][(16 + l15) * 68 + ks2 * 32 + quad * 8];
      #pragma unroll
      for (int no = 0; no < 8; no++) {
        bf16x8 vf = *(const bf16x8*)&Vt[(no * 16 + l15) * 64 +
                                        (((ks2 * 4 + quad) ^ (l15 & 7)) * 8)];
        oacc[0][no] = MFMA16(pf0, vf, oacc[0][no]);
        oacc[1][no] = MFMA16(pf1, vf, oacc[1][no]);
      }
    }
  }

  if (!split) {
    // epilogue: normalize and write bf16
    #pragma unroll
    for (int mt = 0; mt < 2; mt++) {
      f32x4 linv;
      #pragma unroll
      for (int r = 0; r < 4; r++) linv[r] = 1.0f / lrow[mt][r];
      int row = q0 + wave * 32 + mt * 16 + quad * 4;
      #pragma unroll
      for (int no = 0; no < 8; no++) {
        int col = h * 128 + no * 16 + l15;
        #pragma unroll
        for (int r = 0; r < 4; r++)
          Obf[(size_t)(b * 2048 + row + r) * 2048 + col] = (bf16)(oacc[mt][no][r] * linv[r]);
      }
    }
  } else {
    // write f32 partial (unnormalized Oacc + m + l); merge kernel combines after this dispatch
    const int fidx = bh * 6 + (qt - 10);
    float* slot = Part + (size_t)(fidx * 2 + half) * SLOT_F32;
    #pragma unroll
    for (int mt = 0; mt < 2; mt++) {
      int row = wave * 32 + mt * 16 + quad * 4;  // local row 0..127
      #pragma unroll
      for (int no = 0; no < 8; no++) {
        int col = no * 16 + l15;
        #pragma unroll
        for (int r = 0; r < 4; r++)
          slot[(row + r) * 128 + col] = oacc[mt][no][r];
      }
    }
    if (l15 == 0) {
      #pragma unroll
      for (int mt = 0; mt < 2; mt++)
        #pragma unroll
        for (int r = 0; r < 4; r++) {
          int row = wave * 32 + mt * 16 + quad * 4 + r;
          slot[16384 + row] = mrow[mt][r];
          slot[16512 + row] = lrow[mt][r];
        }
    }
  }
}

// ---------------- deterministic split merge: Obf rows for qt>=10 ----------------
__global__ __launch_bounds__(256) void merge_split(const float* __restrict__ Part,
                                                   bf16* __restrict__ Obf) {
  const int fidx = blockIdx.x;        // 0..191
  const int bh = fidx / 6, qt = 10 + fidx % 6;
  const int b = bh >> 4, h = bh & 15;
  const int tid = threadIdx.x;
  const int cl = (tid & 31) * 4;      // column 0..124 step 4
  const int r0 = tid >> 5;            // row stream 0..7
  const float* s0 = Part + (size_t)(fidx * 2) * SLOT_F32;
  const float* s1 = s0 + SLOT_F32;
  #pragma unroll
  for (int i = 0; i < 16; i++) {
    int row = r0 + i * 8;
    float m0 = s0[16384 + row], l0 = s0[16512 + row];
    float m1 = s1[16384 + row], l1 = s1[16512 + row];
    float ms = fmaxf(m0, m1);
    float a0 = EXP2F(m0 - ms), a1 = EXP2F(m1 - ms);
    float linv = 1.0f / (l0 * a0 + l1 * a1);
    f32x4 v0 = *(const f32x4*)&s0[row * 128 + cl];
    f32x4 v1 = *(const f32x4*)&s1[row * 128 + cl];
    bf16x4v o;
    #pragma unroll
    for (int r = 0; r < 4; r++) o[r] = (bf16)((v0[r] * a0 + v1[r] * a1) * linv);
    *(bf16x4v*)&Obf[(size_t)(b * 2048 + qt * 128 + row) * 2048 + h * 128 + cl] = o;
  }
}

extern "C" void kernel_launch(void* const* d_in, const int* in_sizes, int n_in,
                              void* d_out, int out_size, void* d_ws, size_t ws_size,
                              hipStream_t stream) {
  const float* x  = (const float*)d_in[0];
  // d_in[1] = mask: always causal tril; handled analytically.
  const float* Wq = (const float*)d_in[2];
  const float* Wk = (const float*)d_in[3];
  const float* Wv = (const float*)d_in[4];
  const float* Wo = (const float*)d_in[5];
  float* out = (float*)d_out;

  // workspace layout (bf16 elements)
  bf16* Xb    = (bf16*)d_ws;           // 4096x2048
  bf16* Wqkvt = Xb + 8388608;          // 3072x2048 (transposed, fused Q|K|V)
  bf16* Wot   = Wqkvt + 6291456;       // 2048x2048 (transposed)
  bf16* QKV   = Wot + 4194304;         // 4096x3072
  bf16* Obf   = QKV + 12582912;        // 4096x2048
  bf16* Vg    = Obf + 8388608;         // 8 x 128 x 2048 (V^T per (b,kvh))
  // total 83,886,080 bytes

  // split-K partials overlay Xb+Wqkvt (29.36 MB dead after gemm1):
  // 384 slots x 16640 f32 = 25.56 MB.
  float* Part = (float*)d_ws;

  const float qscale = (float)(0.08838834764831845 * 1.4426950408889634);

  cast_f32_bf16<<<8192, 256, 0, stream>>>(x, Xb, 2097152);
  dim3 tb(32, 8);
  transpose_cast<<<dim3(64, 64), tb, 0, stream>>>(Wq, Wqkvt, 2048, 2048, 0, qscale);
  transpose_cast<<<dim3(16, 64), tb, 0, stream>>>(Wk, Wqkvt, 512, 2048, 2048, 1.0f);
  transpose_cast<<<dim3(16, 64), tb, 0, stream>>>(Wv, Wqkvt, 512, 2048, 2560, 1.0f);
  transpose_cast<<<dim3(64, 64), tb, 0, stream>>>(Wo, Wot, 2048, 2048, 0, 1.0f);

  gemm_bt<bf16><<<dim3(24, 32), 256, 0, stream>>>(Xb, Wqkvt, QKV, 4096, 3072, 2048);
  transpose_v<<<dim3(64, 4, 8), tb, 0, stream>>>(QKV, Vg);
  gqa_attn<<<704, 256, 0, stream>>>(QKV, Vg, Obf, Part);
  merge_split<<<192, 256, 0, stream>>>(Part, Obf);
  gemm_bt<float><<<dim3(16, 32), 256, 0, stream>>>(Obf, Wot, out, 4096, 2048, 2048);
}

// Round 5
// 330.907 us; speedup vs baseline: 1.0572x; 1.0185x over previous
//
#include <hip/hip_runtime.h>
#include <hip/hip_bf16.h>
#include <math.h>

typedef __bf16 bf16;
typedef bf16 bf16x8 __attribute__((ext_vector_type(8)));
typedef bf16 bf16x4v __attribute__((ext_vector_type(4)));
typedef float f32x4 __attribute__((ext_vector_type(4)));

#define GLD16(g, l) __builtin_amdgcn_global_load_lds(                          \
    (__attribute__((address_space(1))) void*)(g),                              \
    (__attribute__((address_space(3))) void*)(l), 16, 0, 0)

#define MFMA16(a, b, c) __builtin_amdgcn_mfma_f32_16x16x32_bf16((a), (b), (c), 0, 0, 0)

#if __has_builtin(__builtin_amdgcn_exp2f)
#define EXP2F(x) __builtin_amdgcn_exp2f(x)
#else
#define EXP2F(x) exp2f(x)
#endif

__device__ __forceinline__ f32x4 shfl_xor4(f32x4 a, int m) {
  f32x4 r;
  #pragma unroll
  for (int i = 0; i < 4; i++) r[i] = __shfl_xor(a[i], m);
  return r;
}

// ---------------- cast f32 -> bf16 (vectorized) ----------------
__global__ void cast_f32_bf16(const float* __restrict__ in, bf16* __restrict__ out, int n4) {
  int i = blockIdx.x * blockDim.x + threadIdx.x;
  if (i < n4) {
    float4 v = ((const float4*)in)[i];
    bf16x4v o;
    o.x = (bf16)v.x; o.y = (bf16)v.y; o.z = (bf16)v.z; o.w = (bf16)v.w;
    ((bf16x4v*)out)[i] = o;
  }
}

// ---------------- transpose + cast + scale: out[off + c][r] = in[r][c]*scale ----------------
__global__ void transpose_cast(const float* __restrict__ in, bf16* __restrict__ out,
                               int colsIn, int outStride, int outRowOff, float scale) {
  __shared__ float t[32][33];
  int c0 = blockIdx.x * 32, r0 = blockIdx.y * 32;
  int tx = threadIdx.x, ty = threadIdx.y;  // block (32,8)
  #pragma unroll
  for (int i = 0; i < 32; i += 8)
    t[ty + i][tx] = in[(size_t)(r0 + ty + i) * colsIn + (c0 + tx)];
  __syncthreads();
  #pragma unroll
  for (int i = 0; i < 32; i += 8)
    out[(size_t)(outRowOff + c0 + ty + i) * outStride + (r0 + tx)] = (bf16)(t[tx][ty + i] * scale);
}

// ---------------- V -> V^T global: Vg[(b*4+kvh)][d][n] = QKV[b*2048+n][2560+kvh*128+d] ----------------
__global__ void transpose_v(const bf16* __restrict__ QKV, bf16* __restrict__ Vg) {
  __shared__ bf16 t[32][34];
  int n0 = blockIdx.x * 32, d0 = blockIdx.y * 32;
  int bk = blockIdx.z;
  int b = bk >> 2, kvh = bk & 3;
  const bf16* src = QKV + (size_t)b * 2048 * 3072 + 2560 + kvh * 128;
  bf16* dst = Vg + (size_t)bk * 128 * 2048;
  int tx = threadIdx.x, ty = threadIdx.y;  // block (32,8)
  #pragma unroll
  for (int i = 0; i < 32; i += 8)
    t[ty + i][tx] = src[(size_t)(n0 + ty + i) * 3072 + (d0 + tx)];
  __syncthreads();
  #pragma unroll
  for (int i = 0; i < 32; i += 8)
    dst[(size_t)(d0 + ty + i) * 2048 + (n0 + tx)] = t[tx][ty + i];
}

// ---------------- m97-style GEMM: A[M][K] bf16, Bt[N][K] bf16 -> C[M][N] ----------------
template <typename OutT>
__global__ __launch_bounds__(256, 2) void gemm_bt(const bf16* __restrict__ A,
                                                  const bf16* __restrict__ Bt,
                                                  OutT* __restrict__ C,
                                                  int M, int N, int K) {
  __shared__ __attribute__((aligned(16))) bf16 As[128 * 32];
  __shared__ __attribute__((aligned(16))) bf16 Bs[128 * 32];
  const int tid = threadIdx.x;
  const int lane = tid & 63;
  const int wave = tid >> 6;
  const int wm = wave >> 1, wn = wave & 1;
  const int l15 = lane & 15, quad = lane >> 4;
  const int rowBase = blockIdx.y * 128;
  const int colBase = blockIdx.x * 128;

  f32x4 acc[4][4] = {};

  const int cb0 = wave * 64;
  const int c0 = cb0 + lane;
  const int c1 = c0 + 256;
  const bf16* a0 = A + (size_t)(rowBase + (c0 >> 2)) * K + (c0 & 3) * 8;
  const bf16* a1 = A + (size_t)(rowBase + (c1 >> 2)) * K + (c1 & 3) * 8;
  const bf16* b0 = Bt + (size_t)(colBase + (c0 >> 2)) * K + (c0 & 3) * 8;
  const bf16* b1 = Bt + (size_t)(colBase + (c1 >> 2)) * K + (c1 & 3) * 8;
  bf16* lA0 = &As[cb0 * 8];
  bf16* lA1 = &As[(cb0 + 256) * 8];
  bf16* lB0 = &Bs[cb0 * 8];
  bf16* lB1 = &Bs[(cb0 + 256) * 8];

  for (int k0 = 0; k0 < K; k0 += 32) {
    GLD16(a0 + k0, lA0);
    GLD16(a1 + k0, lA1);
    GLD16(b0 + k0, lB0);
    GLD16(b1 + k0, lB1);
    __syncthreads();
    bf16x8 af[4], bfr[4];
    #pragma unroll
    for (int i = 0; i < 4; i++)
      af[i] = *(const bf16x8*)&As[(wm * 64 + i * 16 + l15) * 32 + quad * 8];
    #pragma unroll
    for (int i = 0; i < 4; i++)
      bfr[i] = *(const bf16x8*)&Bs[(wn * 64 + i * 16 + l15) * 32 + quad * 8];
    #pragma unroll
    for (int i = 0; i < 4; i++)
      #pragma unroll
      for (int j = 0; j < 4; j++)
        acc[i][j] = MFMA16(af[i], bfr[j], acc[i][j]);
    __syncthreads();
  }

  #pragma unroll
  for (int i = 0; i < 4; i++) {
    int row = rowBase + wm * 64 + i * 16 + quad * 4;
    #pragma unroll
    for (int j = 0; j < 4; j++) {
      int col = colBase + wn * 64 + j * 16 + l15;
      #pragma unroll
      for (int r = 0; r < 4; r++)
        C[(size_t)(row + r) * N + col] = (OutT)acc[i][j][r];
    }
  }
}

// ---------------- flash-style GQA attention v7 ----------------
// v5 (balanced split-K, verified R3 @91.8us) + the SAFE subset of v6:
//  (1) ones-column row-sum: l accumulated as extra PV MFMA vs constant ones fragment
//      -> removes 32 ds_bpermute + 32 vadd per tile-wave from the contended LDS pipe.
//  (2) defer-max (T13, log2 THR=8): skip O/l rescale when __all(mx <= mrow+8).
// The R4 raw-asm barrier schedule is WITHDRAWN (correlated with container hang; sync
// structure edits need interactive race screening). Sync = __syncthreads() pair, as verified.
#define MASKV (-1e30f)

// entry code = qt*4 + split*2 + half. CU c gets entries {c>>5, (c>>5)+8, (c>>5)+16}:
// g0:{16,16,2} g1:{15,15,4} g2:{14,14,6} g3:{13,13,8} g4:{12,12,10} g5:{12,11,11}
// g6:{20,14} g7:{18,16}  -- every group sums to 34 tiles.
__device__ const unsigned char BMAP[22] = {
  28, 58, 24, 50, 20, 46, 36, 32,      // e0..e7:  qt7f qt14h0 qt6f qt12h0 qt5f qt11h0 qt9f qt8f
  62, 59, 54, 51, 47, 42, 55, 63,      // e8..e15: qt15h0 qt14h1 qt13h0 qt12h1 qt11h1 qt10h0 qt13h1 qt15h1
  0, 4, 8, 12, 16, 43                  // e16..e21: qt0f qt1f qt2f qt3f qt4f qt10h1
};

#define SLOT_F32 16640  // 128*128 Oacc + 128 m + 128 l

__global__ __launch_bounds__(256, 2) void gqa_attn(const bf16* __restrict__ QKV,
                                                   const bf16* __restrict__ Vg,
                                                   bf16* __restrict__ Obf,
                                                   float* __restrict__ Part) {
  __shared__ __attribute__((aligned(16))) bf16 Kl[64 * 128];   // [key][hd], chunk c' = c ^ (key&7)
  __shared__ __attribute__((aligned(16))) bf16 Vt[128 * 64];   // [hd][key], chunk c' = c ^ (d&7)
  __shared__ __attribute__((aligned(16))) bf16 Pl[4][32 * 68]; // per-wave P, stride 68

  const int tid = threadIdx.x;
  const int lane = tid & 63;
  const int wave = tid >> 6;
  const int l15 = lane & 15, quad = lane >> 4;

  const int e = BMAP[blockIdx.x >> 5];
  const int bh = blockIdx.x & 31;
  const int qt = e >> 2;
  const int split = (e >> 1) & 1;
  const int half = e & 1;
  const int b = bh >> 4, h = bh & 15, kvh = h >> 2;
  const int q0 = qt * 128;
  const int nkt = 2 * qt + 2;
  const int kt_lo = (split && half) ? (nkt >> 1) : 0;
  const int kt_hi = (split && !half) ? (nkt >> 1) : nkt;

  const size_t rs = 3072;
  const bf16* Qb  = QKV + (size_t)b * 2048 * rs + h * 128;
  const bf16* Kb  = QKV + (size_t)b * 2048 * rs + 2048 + kvh * 128;
  const bf16* Vgb = Vg + (size_t)(b * 4 + kvh) * 128 * 2048;

  // Q fragments (already scaled): wave owns rows [q0+wave*32, +32)
  bf16x8 qf[2][4];
  #pragma unroll
  for (int mt = 0; mt < 2; mt++) {
    int row = q0 + wave * 32 + mt * 16 + l15;
    #pragma unroll
    for (int ks = 0; ks < 4; ks++)
      qf[mt][ks] = *(const bf16x8*)&Qb[(size_t)row * rs + ks * 32 + quad * 8];
  }

  // constant all-ones B-fragment for the l-accumulator MFMA
  bf16x8 ones8;
  #pragma unroll
  for (int i = 0; i < 8; i++) ones8[i] = (bf16)1.0f;

  // DMA staging pointers: swizzle folded into per-lane GLOBAL address; LDS base wave-uniform.
  const bf16* kp[4]; const bf16* vp[4];
  bf16* kl[4]; bf16* vl[4];
  #pragma unroll
  for (int t = 0; t < 4; t++) {
    int keyl = wave * 16 + t * 4 + (lane >> 4);
    int ck = (lane & 15) ^ (4 * (t & 1) + (lane >> 4));  // (keyl&7) = 4*(t&1)+(lane>>4)
    kp[t] = Kb + (size_t)(kt_lo * 64 + keyl) * rs + ck * 8;
    kl[t] = &Kl[(wave * 16 + t * 4) * 128];
    int dl = wave * 32 + t * 8 + (lane >> 3);
    int cv = (lane & 7) ^ (lane >> 3);                   // (dl&7) = lane>>3
    vp[t] = Vgb + (size_t)dl * 2048 + kt_lo * 64 + cv * 8;
    vl[t] = &Vt[(wave * 32 + t * 8) * 64];
  }

  f32x4 oacc[2][8] = {};
  f32x4 lacc[2] = {};
  f32x4 mrow[2];
  #pragma unroll
  for (int mt = 0; mt < 2; mt++)
    #pragma unroll
    for (int r = 0; r < 4; r++) mrow[mt][r] = MASKV;

  const int myrow_hi = q0 + wave * 32 + 31;
  for (int kt = kt_lo; kt < kt_hi; kt++) {
    const int k0 = kt * 64;
    __syncthreads();  // previous tile fully consumed by all waves
    #pragma unroll
    for (int t = 0; t < 4; t++) { GLD16(kp[t], kl[t]); kp[t] += 64 * rs; }
    #pragma unroll
    for (int t = 0; t < 4; t++) { GLD16(vp[t], vl[t]); vp[t] += 64; }
    __syncthreads();  // compiler drains vmcnt before barrier -> tiles ready

    if (k0 > myrow_hi) continue;  // wave fully masked for this tile

    // S = Q K^T (log2 domain)
    f32x4 s[2][4] = {};
    #pragma unroll
    for (int ks = 0; ks < 4; ks++) {
      #pragma unroll
      for (int nt = 0; nt < 4; nt++) {
        bf16x8 kf = *(const bf16x8*)&Kl[(nt * 16 + l15) * 128 +
                                        (((ks * 4 + quad) ^ (l15 & 7)) * 8)];
        s[0][nt] = MFMA16(qf[0][ks], kf, s[0][nt]);
        s[1][nt] = MFMA16(qf[1][ks], kf, s[1][nt]);
      }
    }
    // causal mask: only the last two k-tiles can intersect the diagonal (uniform branch)
    if (kt >= nkt - 2) {
      #pragma unroll
      for (int mt = 0; mt < 2; mt++) {
        int rowb = q0 + wave * 32 + mt * 16 + quad * 4;
        #pragma unroll
        for (int nt = 0; nt < 4; nt++) {
          int col = k0 + nt * 16 + l15;
          #pragma unroll
          for (int r = 0; r < 4; r++)
            if (col > rowb + r) s[mt][nt][r] = MASKV;
        }
      }
    }
    // online softmax (log2 domain); l handled by ones-column MFMA in PV
    #pragma unroll
    for (int mt = 0; mt < 2; mt++) {
      f32x4 mx = s[mt][0];
      #pragma unroll
      for (int nt = 1; nt < 4; nt++)
        #pragma unroll
        for (int r = 0; r < 4; r++) mx[r] = fmaxf(mx[r], s[mt][nt][r]);
      #pragma unroll
      for (int d = 1; d < 16; d <<= 1) {
        f32x4 o = shfl_xor4(mx, d);
        #pragma unroll
        for (int r = 0; r < 4; r++) mx[r] = fmaxf(mx[r], o[r]);
      }
      // defer-max (T13): keep old running max while growth <= 8 (p bounded by 2^8)
      bool noresc = (mx[0] <= mrow[mt][0] + 8.f) && (mx[1] <= mrow[mt][1] + 8.f) &&
                    (mx[2] <= mrow[mt][2] + 8.f) && (mx[3] <= mrow[mt][3] + 8.f);
      if (!__all(noresc)) {
        f32x4 alpha;
        #pragma unroll
        for (int r = 0; r < 4; r++) {
          float mn = fmaxf(mrow[mt][r], mx[r]);
          alpha[r] = EXP2F(mrow[mt][r] - mn);
          mrow[mt][r] = mn;
        }
        #pragma unroll
        for (int no = 0; no < 8; no++)
          #pragma unroll
          for (int r = 0; r < 4; r++) oacc[mt][no][r] *= alpha[r];
        #pragma unroll
        for (int r = 0; r < 4; r++) lacc[mt][r] *= alpha[r];
      }
      // P = 2^(s - m): C-layout -> per-wave LDS (A-layout consumable); stride 68
      #pragma unroll
      for (int nt = 0; nt < 4; nt++)
        #pragma unroll
        for (int r = 0; r < 4; r++) {
          float p = EXP2F(s[mt][nt][r] - mrow[mt][r]);
          Pl[wave][(mt * 16 + quad * 4 + r) * 68 + nt * 16 + l15] = (bf16)p;
        }
    }
    // O += P V ; l += P 1 (ones-column row-sum, replaces shuffle-reduce)
    #pragma unroll
    for (int ks2 = 0; ks2 < 2; ks2++) {
      bf16x8 pf0 = *(const bf16x8*)&Pl[wave][l15 * 68 + ks2 * 32 + quad * 8];
      bf16x8 pf1 = *(const bf16x8*)&Pl[wave][(16 + l15) * 68 + ks2 * 32 + quad * 8];
      lacc[0] = MFMA16(pf0, ones8, lacc[0]);
      lacc[1] = MFMA16(pf1, ones8, lacc[1]);
      #pragma unroll
      for (int no = 0; no < 8; no++) {
        bf16x8 vf = *(const bf16x8*)&Vt[(no * 16 + l15) * 64 +
                                        (((ks2 * 4 + quad) ^ (l15 & 7)) * 8)];
        oacc[0][no] = MFMA16(pf0, vf, oacc[0][no]);
        oacc[1][no] = MFMA16(pf1, vf, oacc[1][no]);
      }
    }
  }

  if (!split) {
    // epilogue: normalize and write bf16
    #pragma unroll
    for (int mt = 0; mt < 2; mt++) {
      f32x4 linv;
      #pragma unroll
      for (int r = 0; r < 4; r++) linv[r] = 1.0f / lacc[mt][r];
      int row = q0 + wave * 32 + mt * 16 + quad * 4;
      #pragma unroll
      for (int no = 0; no < 8; no++) {
        int col = h * 128 + no * 16 + l15;
        #pragma unroll
        for (int r = 0; r < 4; r++)
          Obf[(size_t)(b * 2048 + row + r) * 2048 + col] = (bf16)(oacc[mt][no][r] * linv[r]);
      }
    }
  } else {
    // write f32 partial (unnormalized Oacc + m + l); merge kernel combines after this dispatch
    const int fidx = bh * 6 + (qt - 10);
    float* slot = Part + (size_t)(fidx * 2 + half) * SLOT_F32;
    #pragma unroll
    for (int mt = 0; mt < 2; mt++) {
      int row = wave * 32 + mt * 16 + quad * 4;  // local row 0..127
      #pragma unroll
      for (int no = 0; no < 8; no++) {
        int col = no * 16 + l15;
        #pragma unroll
        for (int r = 0; r < 4; r++)
          slot[(row + r) * 128 + col] = oacc[mt][no][r];
      }
    }
    if (l15 == 0) {
      #pragma unroll
      for (int mt = 0; mt < 2; mt++)
        #pragma unroll
        for (int r = 0; r < 4; r++) {
          int row = wave * 32 + mt * 16 + quad * 4 + r;
          slot[16384 + row] = mrow[mt][r];
          slot[16512 + row] = lacc[mt][r];
        }
    }
  }
}

// ---------------- deterministic split merge: Obf rows for qt>=10 ----------------
__global__ __launch_bounds__(256) void merge_split(const float* __restrict__ Part,
                                                   bf16* __restrict__ Obf) {
  const int fidx = blockIdx.x;        // 0..191
  const int bh = fidx / 6, qt = 10 + fidx % 6;
  const int b = bh >> 4, h = bh & 15;
  const int tid = threadIdx.x;
  const int cl = (tid & 31) * 4;      // column 0..124 step 4
  const int r0 = tid >> 5;            // row stream 0..7
  const float* s0 = Part + (size_t)(fidx * 2) * SLOT_F32;
  const float* s1 = s0 + SLOT_F32;
  #pragma unroll
  for (int i = 0; i < 16; i++) {
    int row = r0 + i * 8;
    float m0 = s0[16384 + row], l0 = s0[16512 + row];
    float m1 = s1[16384 + row], l1 = s1[16512 + row];
    float ms = fmaxf(m0, m1);
    float a0 = EXP2F(m0 - ms), a1 = EXP2F(m1 - ms);
    float linv = 1.0f / (l0 * a0 + l1 * a1);
    f32x4 v0 = *(const f32x4*)&s0[row * 128 + cl];
    f32x4 v1 = *(const f32x4*)&s1[row * 128 + cl];
    bf16x4v o;
    #pragma unroll
    for (int r = 0; r < 4; r++) o[r] = (bf16)((v0[r] * a0 + v1[r] * a1) * linv);
    *(bf16x4v*)&Obf[(size_t)(b * 2048 + qt * 128 + row) * 2048 + h * 128 + cl] = o;
  }
}

extern "C" void kernel_launch(void* const* d_in, const int* in_sizes, int n_in,
                              void* d_out, int out_size, void* d_ws, size_t ws_size,
                              hipStream_t stream) {
  const float* x  = (const float*)d_in[0];
  // d_in[1] = mask: always causal tril; handled analytically.
  const float* Wq = (const float*)d_in[2];
  const float* Wk = (const float*)d_in[3];
  const float* Wv = (const float*)d_in[4];
  const float* Wo = (const float*)d_in[5];
  float* out = (float*)d_out;

  // workspace layout (bf16 elements)
  bf16* Xb    = (bf16*)d_ws;           // 4096x2048
  bf16* Wqkvt = Xb + 8388608;          // 3072x2048 (transposed, fused Q|K|V)
  bf16* Wot   = Wqkvt + 6291456;       // 2048x2048 (transposed)
  bf16* QKV   = Wot + 4194304;         // 4096x3072
  bf16* Obf   = QKV + 12582912;        // 4096x2048
  bf16* Vg    = Obf + 8388608;         // 8 x 128 x 2048 (V^T per (b,kvh))
  // total 83,886,080 bytes

  // split-K partials overlay Xb+Wqkvt (29.36 MB dead after gemm1):
  // 384 slots x 16640 f32 = 25.56 MB.
  float* Part = (float*)d_ws;

  const float qscale = (float)(0.08838834764831845 * 1.4426950408889634);

  cast_f32_bf16<<<8192, 256, 0, stream>>>(x, Xb, 2097152);
  dim3 tb(32, 8);
  transpose_cast<<<dim3(64, 64), tb, 0, stream>>>(Wq, Wqkvt, 2048, 2048, 0, qscale);
  transpose_cast<<<dim3(16, 64), tb, 0, stream>>>(Wk, Wqkvt, 512, 2048, 2048, 1.0f);
  transpose_cast<<<dim3(16, 64), tb, 0, stream>>>(Wv, Wqkvt, 512, 2048, 2560, 1.0f);
  transpose_cast<<<dim3(64, 64), tb, 0, stream>>>(Wo, Wot, 2048, 2048, 0, 1.0f);

  gemm_bt<bf16><<<dim3(24, 32), 256, 0, stream>>>(Xb, Wqkvt, QKV, 4096, 3072, 2048);
  transpose_v<<<dim3(64, 4, 8), tb, 0, stream>>>(QKV, Vg);
  gqa_attn<<<704, 256, 0, stream>>>(QKV, Vg, Obf, Part);
  merge_split<<<192, 256, 0, stream>>>(Part, Obf);
  gemm_bt<float><<<dim3(16, 32), 256, 0, stream>>>(Obf, Wot, out, 4096, 2048, 2048);
}